// Round 1
// baseline (265.650 us; speedup 1.0000x reference)
//
#include <hip/hip_runtime.h>

#define BDIM 8192
#define KTOP 3
#define TAU 0.1f
#define MARGIN_MIN 0.1f
#define MARGIN_MAX 0.3f
#define NEG_FILL -50.0f

// insert v into descending top-3 (a >= b >= c)
__device__ __forceinline__ void ins3(float v, float& a, float& b, float& c) {
    if (v > c) {
        if (v > b) {
            if (v > a) { c = b; b = a; a = v; }
            else       { c = b; b = v; }
        } else {
            c = v;
        }
    }
}

__global__ __launch_bounds__(256) void row_topk_loss_kernel(
        const float* __restrict__ in, const int* __restrict__ tg,
        float* __restrict__ rowloss) {
    const int row = blockIdx.x;
    const int t   = threadIdx.x;

    const float4* inr = reinterpret_cast<const float4*>(in + (size_t)row * BDIM);
    const int4*   tgr = reinterpret_cast<const int4*>(tg + (size_t)row * BDIM);

    float a = NEG_FILL, b = NEG_FILL, c = NEG_FILL;

    // 8192 floats / row = 2048 float4; 256 threads -> 8 float4 each, coalesced
    #pragma unroll
    for (int k = 0; k < 8; ++k) {
        const int idx = t + k * 256;
        const float4 v = inr[idx];
        const int4   m = tgr[idx];
        ins3((m.x == 0) ? v.x : NEG_FILL, a, b, c);
        ins3((m.y == 0) ? v.y : NEG_FILL, a, b, c);
        ins3((m.z == 0) ? v.z : NEG_FILL, a, b, c);
        ins3((m.w == 0) ? v.w : NEG_FILL, a, b, c);
    }

    // wave (64-lane) top-3 merge; lanes >= 64-off get garbage but never feed lane 0
    #pragma unroll
    for (int off = 32; off > 0; off >>= 1) {
        const float oa = __shfl_down(a, off, 64);
        const float ob = __shfl_down(b, off, 64);
        const float oc = __shfl_down(c, off, 64);
        ins3(oa, a, b, c);
        ins3(ob, a, b, c);
        ins3(oc, a, b, c);
    }

    __shared__ float sa[4], sb[4], sc[4];
    __shared__ float sdiag;
    if ((t & 63) == 0) {
        const int w = t >> 6;
        sa[w] = a; sb[w] = b; sc[w] = c;
    }
    if (t == 0) sdiag = in[(size_t)row * BDIM + row];
    __syncthreads();

    if (t == 0) {
        float A = sa[0], Bv = sb[0], C = sc[0];
        #pragma unroll
        for (int w = 1; w < 4; ++w) {
            ins3(sa[w], A, Bv, C);
            ins3(sb[w], A, Bv, C);
            ins3(sc[w], A, Bv, C);
        }
        const float sp = sdiag;
        float sn[KTOP] = {A, Bv, C};
        float loss[KTOP], msk[KTOP];
        float mx = -1e30f;
        #pragma unroll
        for (int k = 0; k < KTOP; ++k) {
            float dm = fabsf(sp - sn[k]);
            dm = fminf(fmaxf(dm, MARGIN_MIN), MARGIN_MAX);
            const float l = fmaxf(0.0f, sn[k] - sp + dm);
            loss[k] = l;
            msk[k]  = (l == 0.0f) ? NEG_FILL : sn[k];
            mx = fmaxf(mx, msk[k]);
        }
        float se = 0.0f, num = 0.0f;
        #pragma unroll
        for (int k = 0; k < KTOP; ++k) {
            const float e = __expf((msk[k] - mx) * (1.0f / TAU));
            se  += e;
            num += loss[k] * e;
        }
        rowloss[row] = num / se;
    }
}

// deterministic fixed-order sum of the 8192 per-row losses -> scalar mean
__global__ __launch_bounds__(256) void reduce_kernel(
        const float* __restrict__ rowloss, float* __restrict__ out) {
    __shared__ float s[256];
    const int t = threadIdx.x;
    float sum = 0.0f;
    #pragma unroll
    for (int k = 0; k < 32; ++k) sum += rowloss[t + k * 256];
    s[t] = sum;
    __syncthreads();
    for (int off = 128; off > 0; off >>= 1) {
        if (t < off) s[t] += s[t + off];
        __syncthreads();
    }
    if (t == 0) out[0] = s[0] / (float)(BDIM * KTOP);
}

extern "C" void kernel_launch(void* const* d_in, const int* in_sizes, int n_in,
                              void* d_out, int out_size, void* d_ws, size_t ws_size,
                              hipStream_t stream) {
    const float* in = (const float*)d_in[0];
    const int*   tg = (const int*)d_in[1];
    float* rowloss = (float*)d_ws;   // 8192 floats; every slot rewritten each call
    float* out = (float*)d_out;

    row_topk_loss_kernel<<<BDIM, 256, 0, stream>>>(in, tg, rowloss);
    reduce_kernel<<<1, 256, 0, stream>>>(rowloss, out);
}

// Round 6
// 92.939 us; speedup vs baseline: 2.8583x; 2.8583x over previous
//
#include <hip/hip_runtime.h>

#define BDIM 8192
#define KTOP 3
#define TAU 0.1f
#define MARGIN_MIN 0.1f
#define MARGIN_MAX 0.3f
#define NEG_FILL -50.0f

// branchless insert of v into descending top-3 (a >= b >= c)
__device__ __forceinline__ void ins3(float v, float& a, float& b, float& c) {
    const float mav = fminf(a, v);
    const float mbv = fminf(b, mav);
    a = fmaxf(a, v);
    b = fmaxf(b, mav);
    c = fmaxf(c, mbv);
}

__global__ __launch_bounds__(256) void row_topk_loss_kernel(
        const float* __restrict__ in, const int* __restrict__ tg,
        float* __restrict__ rowloss) {
    const int row = blockIdx.x;
    const int t   = threadIdx.x;

    const float4* inr = reinterpret_cast<const float4*>(in + (size_t)row * BDIM);
    const int4*   tgr = reinterpret_cast<const int4*>(tg + (size_t)row * BDIM);

    // batch all loads first: 8 float4 + 8 int4 in flight per thread
    float4 v[8];
    int4   m[8];
    #pragma unroll
    for (int k = 0; k < 8; ++k) v[k] = inr[t + k * 256];
    #pragma unroll
    for (int k = 0; k < 8; ++k) m[k] = tgr[t + k * 256];

    float a = NEG_FILL, b = NEG_FILL, c = NEG_FILL;
    #pragma unroll
    for (int k = 0; k < 8; ++k) {
        ins3((m[k].x == 0) ? v[k].x : NEG_FILL, a, b, c);
        ins3((m[k].y == 0) ? v[k].y : NEG_FILL, a, b, c);
        ins3((m[k].z == 0) ? v[k].z : NEG_FILL, a, b, c);
        ins3((m[k].w == 0) ? v[k].w : NEG_FILL, a, b, c);
    }

    // 64-lane wave top-3 merge (branchless ins3 -> no divergence)
    #pragma unroll
    for (int off = 32; off > 0; off >>= 1) {
        const float oa = __shfl_down(a, off, 64);
        const float ob = __shfl_down(b, off, 64);
        const float oc = __shfl_down(c, off, 64);
        ins3(oa, a, b, c);
        ins3(ob, a, b, c);
        ins3(oc, a, b, c);
    }

    __shared__ float sa[4], sb[4], sc[4];
    __shared__ float sdiag;
    if ((t & 63) == 0) {
        const int w = t >> 6;
        sa[w] = a; sb[w] = b; sc[w] = c;
    }
    if (t == 0) sdiag = in[(size_t)row * BDIM + row];
    __syncthreads();

    if (t == 0) {
        float A = sa[0], Bv = sb[0], C = sc[0];
        #pragma unroll
        for (int w = 1; w < 4; ++w) {
            ins3(sa[w], A, Bv, C);
            ins3(sb[w], A, Bv, C);
            ins3(sc[w], A, Bv, C);
        }
        const float sp = sdiag;
        float sn[KTOP] = {A, Bv, C};
        float loss[KTOP], msk[KTOP];
        float mx = -1e30f;
        #pragma unroll
        for (int k = 0; k < KTOP; ++k) {
            float dm = fabsf(sp - sn[k]);
            dm = fminf(fmaxf(dm, MARGIN_MIN), MARGIN_MAX);
            const float l = fmaxf(0.0f, sn[k] - sp + dm);
            loss[k] = l;
            msk[k]  = (l == 0.0f) ? NEG_FILL : sn[k];
            mx = fmaxf(mx, msk[k]);
        }
        float se = 0.0f, num = 0.0f;
        #pragma unroll
        for (int k = 0; k < KTOP; ++k) {
            const float e = __expf((msk[k] - mx) * (1.0f / TAU));
            se  += e;
            num += loss[k] * e;
        }
        rowloss[row] = num / se;
    }
}

// deterministic fixed-order sum of the 8192 per-row losses -> scalar mean
__global__ __launch_bounds__(256) void reduce_kernel(
        const float* __restrict__ rowloss, float* __restrict__ out) {
    __shared__ float s[256];
    const int t = threadIdx.x;
    float sum = 0.0f;
    #pragma unroll
    for (int k = 0; k < 32; ++k) sum += rowloss[t + k * 256];
    s[t] = sum;
    __syncthreads();
    for (int off = 128; off > 0; off >>= 1) {
        if (t < off) s[t] += s[t + off];
        __syncthreads();
    }
    if (t == 0) out[0] = s[0] / (float)(BDIM * KTOP);
}

extern "C" void kernel_launch(void* const* d_in, const int* in_sizes, int n_in,
                              void* d_out, int out_size, void* d_ws, size_t ws_size,
                              hipStream_t stream) {
    const float* in = (const float*)d_in[0];
    const int*   tg = (const int*)d_in[1];
    float* rowloss = (float*)d_ws;   // 8192 floats; every slot rewritten each call
    float* out = (float*)d_out;

    row_topk_loss_kernel<<<BDIM, 256, 0, stream>>>(in, tg, rowloss);
    reduce_kernel<<<1, 256, 0, stream>>>(rowloss, out);
}